// Round 1
// baseline (656.549 us; speedup 1.0000x reference)
//
#include <hip/hip_runtime.h>
#include <stdint.h>

// WinnerCombiner: B=64, L=4096, K=64
// decay = f32(e^-0.5), correctly rounded
#define DECAY   0.6065306597126334f
#define GAIN    0.5f
#define INV_T   10.0f
#define C_MEAN  0.015625f   // 1/64
#define EPS_SUR 1e-6f

#define B_DIM 64
#define L_DIM 4096
#define K_DIM 64

// ---- DPP wave-64 reductions (all inputs are >= 0, so bound_ctrl 0-fill is identity-safe) ----
__device__ __forceinline__ float wave_max_bcast(float x) {
    int v;
    v = __builtin_amdgcn_update_dpp(0, __float_as_int(x), 0x111, 0xf, 0xf, true); x = fmaxf(x, __int_as_float(v)); // row_shr:1
    v = __builtin_amdgcn_update_dpp(0, __float_as_int(x), 0x112, 0xf, 0xf, true); x = fmaxf(x, __int_as_float(v)); // row_shr:2
    v = __builtin_amdgcn_update_dpp(0, __float_as_int(x), 0x114, 0xf, 0xf, true); x = fmaxf(x, __int_as_float(v)); // row_shr:4
    v = __builtin_amdgcn_update_dpp(0, __float_as_int(x), 0x118, 0xf, 0xf, true); x = fmaxf(x, __int_as_float(v)); // row_shr:8
    v = __builtin_amdgcn_update_dpp(0, __float_as_int(x), 0x142, 0xf, 0xf, true); x = fmaxf(x, __int_as_float(v)); // row_bcast:15
    v = __builtin_amdgcn_update_dpp(0, __float_as_int(x), 0x143, 0xf, 0xf, true); x = fmaxf(x, __int_as_float(v)); // row_bcast:31
    // lane 63 now holds the full-wave max; broadcast it
    return __int_as_float(__builtin_amdgcn_readlane(__float_as_int(x), 63));
}

__device__ __forceinline__ float wave_sum_bcast(float x) {
    int v;
    v = __builtin_amdgcn_update_dpp(0, __float_as_int(x), 0x111, 0xf, 0xf, true); x += __int_as_float(v);
    v = __builtin_amdgcn_update_dpp(0, __float_as_int(x), 0x112, 0xf, 0xf, true); x += __int_as_float(v);
    v = __builtin_amdgcn_update_dpp(0, __float_as_int(x), 0x114, 0xf, 0xf, true); x += __int_as_float(v);
    v = __builtin_amdgcn_update_dpp(0, __float_as_int(x), 0x118, 0xf, 0xf, true); x += __int_as_float(v);
    v = __builtin_amdgcn_update_dpp(0, __float_as_int(x), 0x142, 0xf, 0xf, true); x += __int_as_float(v);
    v = __builtin_amdgcn_update_dpp(0, __float_as_int(x), 0x143, 0xf, 0xf, true); x += __int_as_float(v);
    return __int_as_float(__builtin_amdgcn_readlane(__float_as_int(x), 63));
}

// ---- K1: sequential winner recurrence. 64 blocks (one per batch) x 64 lanes (one per channel).
// Writes idx (as float), vals, and z checkpoints every 64 steps.
__global__ __launch_bounds__(64) void k1_seq(const float* __restrict__ d2,
                                             float* __restrict__ out_idx,
                                             float* __restrict__ out_vals,
                                             float* __restrict__ zchk) {
    const int b    = blockIdx.x;
    const int lane = threadIdx.x;
    const float* p = d2 + (size_t)b * L_DIM * K_DIM + lane;

    float buf[16];
#pragma unroll
    for (int u = 0; u < 16; ++u) buf[u] = p[(size_t)u * K_DIM];

    float z = 0.0f;
    float idx_hold = 0.0f, val_hold = 0.0f;

    for (int g = 0; g < 256; ++g) {           // 256 groups of 16 steps
        if ((g & 3) == 0) {                   // chunk start (every 64 steps): checkpoint z
            zchk[(((size_t)b << 6) + (size_t)(g >> 2)) * K_DIM + lane] = z;
        }
#pragma unroll
        for (int u = 0; u < 16; ++u) {
            const int t = (g << 4) + u;
            float d2v = buf[u];
            // prefetch t+16 (clamped; tail value unused)
            int tn = t + 16; if (tn > L_DIM - 1) tn = L_DIM - 1;
            buf[u] = p[(size_t)tn * K_DIM];

            // score = d2 + 0.5*z  (no FMA: match numpy mul-then-add exactly)
            float score = __fadd_rn(d2v, __fmul_rn(GAIN, z));

            // argmax with first-index tie-break
            float m = wave_max_bcast(score);
            unsigned long long mask = __ballot(score == m);
            int win = (int)__ffsll(mask) - 1;

            float hard = (lane == win) ? 1.0f : 0.0f;
            float val  = __int_as_float(__builtin_amdgcn_readlane(__float_as_int(d2v), win));

            // lane (t & 63) holds this step's outputs for a coalesced store every 64 steps
            int slot = ((g & 3) << 4) | u;
            if (lane == slot) { idx_hold = (float)win; val_hold = val; }

            // z update (no FMA)
            z = __fadd_rn(__fmul_rn(z, DECAY), hard);
        }
        if ((g & 3) == 3) {
            size_t o = ((size_t)b << 12) + ((size_t)(g >> 2) << 6) + lane;
            out_idx[o]  = idx_hold;
            out_vals[o] = val_hold;
        }
    }
}

// ---- K2: parallel replay. 4096 blocks (64 chunks x 64 batches) x 64 lanes.
// Reads z checkpoint + idx, recomputes score/softmax/w_sur/w/soma_in.
__global__ __launch_bounds__(64) void k2_par(const float* __restrict__ d2,
                                             const float* __restrict__ in_idx,
                                             const float* __restrict__ zchk,
                                             float* __restrict__ out_w,
                                             float* __restrict__ out_soma) {
    const int c    = blockIdx.x & 63;     // chunk
    const int b    = blockIdx.x >> 6;     // batch
    const int lane = threadIdx.x;

    const size_t rowbase = ((size_t)b << 12) + ((size_t)c << 6);  // b*L + c*64
    const float* p = d2 + rowbase * K_DIM + lane;

    float z  = zchk[(((size_t)b << 6) + (size_t)c) * K_DIM + lane];
    float fI = in_idx[rowbase + lane];
    int   vI = (int)fI;                    // per-lane: winner of step (chunk*64 + lane)

    float buf[8];
#pragma unroll
    for (int u = 0; u < 8; ++u) buf[u] = p[(size_t)u * K_DIM];

    float soma_hold = 0.0f;

    for (int s8 = 0; s8 < 8; ++s8) {
#pragma unroll
        for (int u = 0; u < 8; ++u) {
            const int s = (s8 << 3) + u;
            float d2v = buf[u];
            int sn = s + 8; if (sn > 63) sn = 63;
            buf[u] = p[(size_t)sn * K_DIM];

            // identical ops to K1 -> bit-identical score
            float score = __fadd_rn(d2v, __fmul_rn(GAIN, z));

            int   iwin = __builtin_amdgcn_readlane(vI, s);
            float m    = __int_as_float(__builtin_amdgcn_readlane(__float_as_int(score), iwin));

            float e    = __expf((score - m) * INV_T);
            float ssum = wave_sum_bcast(e);
            float soft = e / ssum;
            float inhib = fmaxf(soft - C_MEAN, 0.0f);
            float isum = wave_sum_bcast(inhib) + EPS_SUR;
            float wsur = inhib / isum;
            float hard = (lane == iwin) ? 1.0f : 0.0f;
            float w    = (hard - wsur) + wsur;   // straight-through forward value

            out_w[(rowbase + (size_t)s) * K_DIM + lane] = w;

            float soma = wave_sum_bcast(__fmul_rn(w, d2v));
            if (lane == s) soma_hold = soma;

            z = __fadd_rn(__fmul_rn(z, DECAY), hard);
        }
    }
    out_soma[rowbase + lane] = soma_hold;
}

extern "C" void kernel_launch(void* const* d_in, const int* in_sizes, int n_in,
                              void* d_out, int out_size, void* d_ws, size_t ws_size,
                              hipStream_t stream) {
    (void)in_sizes; (void)n_in; (void)out_size; (void)ws_size;

    const float* d2 = (const float*)d_in[0];
    float* out = (float*)d_out;

    const size_t BL = (size_t)B_DIM * L_DIM;          // 262144
    float* out_idx  = out;                            // [B, L]
    float* out_vals = out + BL;                       // [B, L]
    float* out_w    = out + 2 * BL;                   // [B, L, K]
    float* out_soma = out + 2 * BL + BL * K_DIM;      // [B, L]

    float* zchk = (float*)d_ws;                       // [B, 64, K] = 4 MB

    hipLaunchKernelGGL(k1_seq, dim3(B_DIM), dim3(64), 0, stream,
                       d2, out_idx, out_vals, zchk);
    hipLaunchKernelGGL(k2_par, dim3(B_DIM * 64), dim3(64), 0, stream,
                       d2, out_idx, zchk, out_w, out_soma);
}